// Round 16
// baseline (308.688 us; speedup 1.0000x reference)
//
#include <hip/hip_runtime.h>

#define HDIM 256
#define DDIM 128
#define VSZ 14

typedef __bf16 bf16x8 __attribute__((ext_vector_type(8)));
typedef float f32x4 __attribute__((ext_vector_type(4)));

static __device__ __forceinline__ unsigned short f2bf(float f) {
  unsigned u = __builtin_bit_cast(unsigned, f);
  u += 0x7FFF + ((u >> 16) & 1);  // round-to-nearest-even
  return (unsigned short)(u >> 16);
}
static __device__ __forceinline__ float bf2f(unsigned short u) {
  unsigned x = ((unsigned)u) << 16;
  return __builtin_bit_cast(float, x);
}
static __device__ __forceinline__ unsigned pack2(float a, float b) {
  return (unsigned)f2bf(a) | ((unsigned)f2bf(b) << 16);
}
// unpack 8 bf16 (as uint4) -> 8 f32
static __device__ __forceinline__ void ub8(uint4 p, float* o) {
  o[0] = __builtin_bit_cast(float, p.x << 16);
  o[1] = __builtin_bit_cast(float, p.x & 0xFFFF0000u);
  o[2] = __builtin_bit_cast(float, p.y << 16);
  o[3] = __builtin_bit_cast(float, p.y & 0xFFFF0000u);
  o[4] = __builtin_bit_cast(float, p.z << 16);
  o[5] = __builtin_bit_cast(float, p.z & 0xFFFF0000u);
  o[6] = __builtin_bit_cast(float, p.w << 16);
  o[7] = __builtin_bit_cast(float, p.w & 0xFFFF0000u);
}

// ---------- CSR construction ----------

__global__ void k_count(const int* __restrict__ dst, int* __restrict__ cnt, int E) {
  int i = blockIdx.x * 256 + threadIdx.x;
  if (i < E) atomicAdd(&cnt[dst[i]], 1);
}

// block-local scan + one atomic per block for the base; emits dinv + packed node info
__global__ void k_alloc(const int* __restrict__ cnt, int* __restrict__ off,
                        float* __restrict__ dinv, int2* __restrict__ ninfo,
                        const int* __restrict__ ids, int* __restrict__ total, int n) {
  __shared__ int s[256];
  __shared__ int base;
  int i = blockIdx.x * 256 + threadIdx.x;
  int c = (i < n) ? cnt[i] : 0;
  if (i < n) {
    float dv = rsqrtf((float)(c + 1));  // +1 self-loop
    dinv[i] = dv;
    int2 inf;
    inf.x = ids[i];
    inf.y = __builtin_bit_cast(int, dv);
    ninfo[i] = inf;
  }
  s[threadIdx.x] = c;
  __syncthreads();
  for (int d = 1; d < 256; d <<= 1) {
    int add = (threadIdx.x >= d) ? s[threadIdx.x - d] : 0;
    __syncthreads();
    s[threadIdx.x] += add;
    __syncthreads();
  }
  if (threadIdx.x == 255) base = atomicAdd(total, s[255]);
  __syncthreads();
  if (i < n) off[i] = base + s[threadIdx.x] - c;
}

// packed edge record: {src | id<<24, dinv(src) bits} (8 B)
__global__ void k_fill(const int* __restrict__ src, const int* __restrict__ dst,
                       const int2* __restrict__ ninfo, const int* __restrict__ off,
                       int* __restrict__ cur, int2* __restrict__ edata, int E) {
  int i = blockIdx.x * 256 + threadIdx.x;
  if (i >= E) return;
  int d = dst[i];
  int p = off[d] + atomicAdd(&cur[d], 1);
  int s = src[i];
  int2 inf = ninfo[s];
  int2 v;
  v.x = s | (inf.x << 24);
  v.y = inf.y;
  edata[p] = v;
}

// ---------- fused prologue precomputes ----------
// blocks [0,128): W transpose+cvt; [128,142): embW; [142,145): BN; [145,..): goff

__global__ __launch_bounds__(256) void k_prep(
    const float* __restrict__ emb, const float* __restrict__ Ws,
    const float* __restrict__ bs, const float* __restrict__ gam,
    const float* __restrict__ bet, const float* __restrict__ mu,
    const float* __restrict__ va, const int* __restrict__ batch,
    float* __restrict__ embW, float* __restrict__ Ac, float* __restrict__ Bc,
    unsigned short* __restrict__ Wtb, int* __restrict__ goff, int G, int n) {
  int b = blockIdx.x;
  if (b < 128) {
    __shared__ float tile[32][33];
    int layer = b >> 6;
    int tb = b & 63;
    int bx = (tb & 7) * 32, by = (tb >> 3) * 32;
    const float* W = Ws + (size_t)(layer + 1) * HDIM * HDIM;
    unsigned short* Wt = Wtb + (size_t)layer * HDIM * HDIM;
    int tx = threadIdx.x & 31, ty = threadIdx.x >> 5;
#pragma unroll
    for (int i = 0; i < 4; ++i)
      tile[ty + i * 8][tx] = W[(size_t)(by + ty + i * 8) * HDIM + bx + tx];
    __syncthreads();
#pragma unroll
    for (int i = 0; i < 4; ++i)
      Wt[(size_t)(bx + ty + i * 8) * HDIM + by + tx] = f2bf(tile[tx][ty + i * 8]);
  } else if (b < 142) {
    int t = b - 128, j = threadIdx.x;
    float acc = 0.f;
    for (int k = 0; k < HDIM; ++k) acc = fmaf(emb[t * HDIM + k], Ws[k * HDIM + j], acc);
    embW[t * HDIM + j] = acc;
  } else if (b < 145) {
    int i = (b - 142) * HDIM + threadIdx.x;
    float a = gam[i] * rsqrtf(va[i] + 1e-5f);
    Ac[i] = a;
    Bc[i] = (bs[i] - mu[i]) * a + bet[i];
  } else {
    int g = (b - 145) * 256 + threadIdx.x;
    if (g > G) return;
    int lo = 0, hi = n;
    while (lo < hi) {
      int mid = (lo + hi) >> 1;
      if (batch[mid] < g) lo = mid + 1;
      else hi = mid;
    }
    goff[g] = lo;
  }
}

// ---------- layer 1: aggregate bf16 14-row table (LDS) + BN + ReLU -> bf16 ----------

__global__ __launch_bounds__(256) void k_layer1(
    const int* __restrict__ ids, const float* __restrict__ embW,
    const int* __restrict__ off, const int* __restrict__ deg,
    const int2* __restrict__ edata, const float* __restrict__ dinv,
    const float* __restrict__ A, const float* __restrict__ B,
    unsigned short* __restrict__ Y, int n) {
  __shared__ unsigned short lw[VSZ * HDIM];
  for (int i = threadIdx.x; i < VSZ * HDIM; i += 256) lw[i] = f2bf(embW[i]);
  __syncthreads();
  int j = (threadIdx.x & 31) * 8;
  float4 a0 = *reinterpret_cast<const float4*>(&A[j]);
  float4 a1 = *reinterpret_cast<const float4*>(&A[j + 4]);
  float4 b0 = *reinterpret_cast<const float4*>(&B[j]);
  float4 b1 = *reinterpret_cast<const float4*>(&B[j + 4]);
  int nb = (n + 7) >> 3;
  for (int b = blockIdx.x; b < nb; b += gridDim.x) {
    int v = b * 8 + (threadIdx.x >> 5);
    if (v >= n) continue;
    float dv = dinv[v];
    float s = dv * dv;
    float acc[8], m[8];
    uint4 x = *reinterpret_cast<const uint4*>(&lw[ids[v] * HDIM + j]);
    ub8(x, acc);
#pragma unroll
    for (int i = 0; i < 8; ++i) acc[i] *= s;
    int e = off[v], e1 = e + deg[v];
    for (; e + 3 < e1; e += 4) {
      int2 d0 = edata[e], d1 = edata[e + 1], d2 = edata[e + 2], d3 = edata[e + 3];
      uint4 g0 = *reinterpret_cast<const uint4*>(&lw[((unsigned)d0.x >> 24) * HDIM + j]);
      uint4 g1 = *reinterpret_cast<const uint4*>(&lw[((unsigned)d1.x >> 24) * HDIM + j]);
      uint4 g2 = *reinterpret_cast<const uint4*>(&lw[((unsigned)d2.x >> 24) * HDIM + j]);
      uint4 g3 = *reinterpret_cast<const uint4*>(&lw[((unsigned)d3.x >> 24) * HDIM + j]);
      float w0 = dv * __builtin_bit_cast(float, d0.y);
      float w1 = dv * __builtin_bit_cast(float, d1.y);
      float w2 = dv * __builtin_bit_cast(float, d2.y);
      float w3 = dv * __builtin_bit_cast(float, d3.y);
      ub8(g0, m);
#pragma unroll
      for (int i = 0; i < 8; ++i) acc[i] = fmaf(w0, m[i], acc[i]);
      ub8(g1, m);
#pragma unroll
      for (int i = 0; i < 8; ++i) acc[i] = fmaf(w1, m[i], acc[i]);
      ub8(g2, m);
#pragma unroll
      for (int i = 0; i < 8; ++i) acc[i] = fmaf(w2, m[i], acc[i]);
      ub8(g3, m);
#pragma unroll
      for (int i = 0; i < 8; ++i) acc[i] = fmaf(w3, m[i], acc[i]);
    }
    for (; e < e1; ++e) {
      int2 d0 = edata[e];
      uint4 g0 = *reinterpret_cast<const uint4*>(&lw[((unsigned)d0.x >> 24) * HDIM + j]);
      float w0 = dv * __builtin_bit_cast(float, d0.y);
      ub8(g0, m);
#pragma unroll
      for (int i = 0; i < 8; ++i) acc[i] = fmaf(w0, m[i], acc[i]);
    }
    float o[8];
    o[0] = fmaxf(fmaf(acc[0], a0.x, b0.x), 0.f);
    o[1] = fmaxf(fmaf(acc[1], a0.y, b0.y), 0.f);
    o[2] = fmaxf(fmaf(acc[2], a0.z, b0.z), 0.f);
    o[3] = fmaxf(fmaf(acc[3], a0.w, b0.w), 0.f);
    o[4] = fmaxf(fmaf(acc[4], a1.x, b1.x), 0.f);
    o[5] = fmaxf(fmaf(acc[5], a1.y, b1.y), 0.f);
    o[6] = fmaxf(fmaf(acc[6], a1.z, b1.z), 0.f);
    o[7] = fmaxf(fmaf(acc[7], a1.w, b1.w), 0.f);
    uint4 st;
    st.x = pack2(o[0], o[1]);
    st.y = pack2(o[2], o[3]);
    st.z = pack2(o[4], o[5]);
    st.w = pack2(o[6], o[7]);
    *reinterpret_cast<uint4*>(&Y[(size_t)v * HDIM + j]) = st;
  }
}

// ---------- aggregation: bf16 gather -> bf16 out, half-wave per node, grid-stride ----------

__global__ __launch_bounds__(256) void k_agg(
    const unsigned short* __restrict__ X, const int* __restrict__ off,
    const int* __restrict__ deg, const int2* __restrict__ edata,
    const float* __restrict__ dinv, unsigned short* __restrict__ Yb, int n) {
  int j = (threadIdx.x & 31) * 8;
  int nb = (n + 7) >> 3;
  for (int b = blockIdx.x; b < nb; b += gridDim.x) {
    int v = b * 8 + (threadIdx.x >> 5);
    if (v >= n) continue;
    float dv = dinv[v];
    float s = dv * dv;
    float acc[8], m[8];
    uint4 x = *reinterpret_cast<const uint4*>(&X[(size_t)v * HDIM + j]);
    ub8(x, acc);
#pragma unroll
    for (int i = 0; i < 8; ++i) acc[i] *= s;
    int e = off[v], e1 = e + deg[v];
    for (; e + 3 < e1; e += 4) {
      int2 d0 = edata[e], d1 = edata[e + 1], d2 = edata[e + 2], d3 = edata[e + 3];
      uint4 g0 = *reinterpret_cast<const uint4*>(&X[(size_t)(d0.x & 0xFFFFFF) * HDIM + j]);
      uint4 g1 = *reinterpret_cast<const uint4*>(&X[(size_t)(d1.x & 0xFFFFFF) * HDIM + j]);
      uint4 g2 = *reinterpret_cast<const uint4*>(&X[(size_t)(d2.x & 0xFFFFFF) * HDIM + j]);
      uint4 g3 = *reinterpret_cast<const uint4*>(&X[(size_t)(d3.x & 0xFFFFFF) * HDIM + j]);
      float w0 = dv * __builtin_bit_cast(float, d0.y);
      float w1 = dv * __builtin_bit_cast(float, d1.y);
      float w2 = dv * __builtin_bit_cast(float, d2.y);
      float w3 = dv * __builtin_bit_cast(float, d3.y);
      ub8(g0, m);
#pragma unroll
      for (int i = 0; i < 8; ++i) acc[i] = fmaf(w0, m[i], acc[i]);
      ub8(g1, m);
#pragma unroll
      for (int i = 0; i < 8; ++i) acc[i] = fmaf(w1, m[i], acc[i]);
      ub8(g2, m);
#pragma unroll
      for (int i = 0; i < 8; ++i) acc[i] = fmaf(w2, m[i], acc[i]);
      ub8(g3, m);
#pragma unroll
      for (int i = 0; i < 8; ++i) acc[i] = fmaf(w3, m[i], acc[i]);
    }
    for (; e < e1; ++e) {
      int2 d0 = edata[e];
      uint4 g0 = *reinterpret_cast<const uint4*>(&X[(size_t)(d0.x & 0xFFFFFF) * HDIM + j]);
      float w0 = dv * __builtin_bit_cast(float, d0.y);
      ub8(g0, m);
#pragma unroll
      for (int i = 0; i < 8; ++i) acc[i] = fmaf(w0, m[i], acc[i]);
    }
    uint4 st;
    st.x = pack2(acc[0], acc[1]);
    st.y = pack2(acc[2], acc[3]);
    st.z = pack2(acc[4], acc[5]);
    st.w = pack2(acc[6], acc[7]);
    *reinterpret_cast<uint4*>(&Yb[(size_t)v * HDIM + j]) = st;
  }
}

// ---------- bf16 MFMA GEMM (M x 256) @ (256 x 256) + BN + ReLU ----------
// BARRIER-FREE K-loop: MFMA fragments loaded DIRECTLY from global (A rows are
// consumed once per block; Wt is 128 KB L2-hot), so waves pipeline
// independently instead of lockstep-stalling on staging barriers (round-15
// counters: MfmaUtil 10%, all waves draining vmcnt together 8x per block).
// LDS is only the C-stage. Bijective XCD swizzle keeps the A-sharing tile
// pair {2m,2m+1} on one XCD (round-15: FETCH 51->26 MB).
// POOL=false: -> bf16 Y rows; POOL=true: -> segmented sums into pooled[G][256].

#define BM 128
#define BN 128
#define LDC 136  // C-stage row stride (elements)

template <bool POOL>
__global__ __launch_bounds__(256) void k_gemm_mfma(
    const unsigned short* __restrict__ Xb, const unsigned short* __restrict__ Wt,
    const float* __restrict__ Asc, const float* __restrict__ Bsh,
    unsigned short* __restrict__ Y, float* __restrict__ pooled,
    const int* __restrict__ batch, int M) {
  __shared__ uint4 smem4[BM * LDC / 8];  // 34816 B C-stage
  __shared__ int gid[BM];
  unsigned short* Cs = reinterpret_cast<unsigned short*>(smem4);
  int t = threadIdx.x;

  // bijective XCD swizzle (m204): orig -> wgid so consecutive wgid share an XCD
  int nwg = gridDim.x;
  int qq = nwg >> 3, rr = nwg & 7;
  int xcd = blockIdx.x & 7, idx = blockIdx.x >> 3;
  int wg = (xcd < rr ? xcd * (qq + 1) : rr * (qq + 1) + (xcd - rr) * qq) + idx;
  int m0 = (wg >> 1) * BM;
  int n0 = (wg & 1) * BN;

  int l = t & 63, w = t >> 6;
  int wm = w & 1, wn = w >> 1;
  int cl = l & 15, q = l >> 4;

  if (POOL && t < BM) {
    int gr = m0 + t;
    gid[t] = (gr < M) ? batch[gr] : -1;  // covered by pre-store barrier
  }

  f32x4 acc[4][4];
  f32x4 zf = {0.f, 0.f, 0.f, 0.f};
#pragma unroll
  for (int i = 0; i < 4; ++i)
#pragma unroll
    for (int jj = 0; jj < 4; ++jj) acc[i][jj] = zf;

  // per-lane fragment row pointers (A rows clamped at M edge)
  const unsigned short* ap[4];
  const unsigned short* bp[4];
#pragma unroll
  for (int i = 0; i < 4; ++i) {
    int ar = m0 + wm * 64 + i * 16 + cl;
    if (ar > M - 1) ar = M - 1;
    ap[i] = &Xb[(size_t)ar * HDIM + q * 8];
    bp[i] = &Wt[(size_t)(n0 + wn * 64 + i * 16 + cl) * HDIM + q * 8];
  }

  for (int k0 = 0; k0 < HDIM; k0 += 32) {
    bf16x8 af[4], bfr[4];
#pragma unroll
    for (int i = 0; i < 4; ++i)
      af[i] = *reinterpret_cast<const bf16x8*>(ap[i] + k0);
#pragma unroll
    for (int jj = 0; jj < 4; ++jj)
      bfr[jj] = *reinterpret_cast<const bf16x8*>(bp[jj] + k0);
#pragma unroll
    for (int i = 0; i < 4; ++i)
#pragma unroll
      for (int jj = 0; jj < 4; ++jj)
        acc[i][jj] = __builtin_amdgcn_mfma_f32_16x16x32_bf16(af[i], bfr[jj], acc[i][jj], 0, 0, 0);
  }

  // ---- epilogue: BN + ReLU -> LDS C-stage ----
#pragma unroll
  for (int jj = 0; jj < 4; ++jj) {
    int col = wn * 64 + jj * 16 + cl;
    float as = Asc[n0 + col], bsv = Bsh[n0 + col];
#pragma unroll
    for (int i = 0; i < 4; ++i) {
      int rowb = wm * 64 + i * 16 + q * 4;
#pragma unroll
      for (int r = 0; r < 4; ++r)
        Cs[(rowb + r) * LDC + col] = f2bf(fmaxf(fmaf(acc[i][jj][r], as, bsv), 0.f));
    }
  }
  __syncthreads();
  if (!POOL) {
#pragma unroll
    for (int c = 0; c < 8; ++c) {
      int idx2 = t + 256 * c;            // 0..2047 : 128 rows x 16 uint4-chunks
      int row = idx2 >> 4, cq = (idx2 & 15) * 8;
      int gr = m0 + row;
      if (gr < M)
        *reinterpret_cast<uint4*>(&Y[(size_t)gr * HDIM + n0 + cq]) =
            *reinterpret_cast<const uint4*>(&Cs[row * LDC + cq]);
    }
  } else {
    // segmented column-sum; gid in LDS, fixed-trip loop (wave-uniform branches)
    int col = t & 127;
    int rbeg = (t >> 7) * 64;
    float sum = 0.f;
    int gprev = -1;
#pragma unroll 16
    for (int rr2 = 0; rr2 < 64; ++rr2) {
      int r = rbeg + rr2;
      int g = gid[r];
      if (g != gprev) {
        if (gprev >= 0) atomicAdd(&pooled[(size_t)gprev * HDIM + n0 + col], sum);
        sum = 0.f;
        gprev = g;
      }
      if (g >= 0) sum += bf2f(Cs[r * LDC + col]);
    }
    if (gprev >= 0) atomicAdd(&pooled[(size_t)gprev * HDIM + n0 + col], sum);
  }
}

// ---------- final projection (divides pooled sums by graph size) ----------

__global__ __launch_bounds__(128) void k_proj(
    const float* __restrict__ P, const int* __restrict__ goff,
    const float* __restrict__ W, const float* __restrict__ bias,
    float* __restrict__ out, int G) {
  __shared__ float rows[8][HDIM];
  __shared__ float sinv[8];
  int g0 = blockIdx.x * 8;
  if (threadIdx.x < 8) {
    int g = g0 + threadIdx.x;
    float c = (g < G) ? (float)(goff[g + 1] - goff[g]) : 1.f;
    sinv[threadIdx.x] = 1.f / fmaxf(c, 1.f);
  }
  __syncthreads();
  for (int i = threadIdx.x; i < 8 * HDIM; i += 128) {
    int qg = i >> 8;
    int g = g0 + qg;
    rows[qg][i & 255] = (g < G) ? P[(size_t)g * HDIM + (i & 255)] * sinv[qg] : 0.f;
  }
  __syncthreads();
  int d = threadIdx.x;
  float bb = bias[d];
  float acc[8] = {bb, bb, bb, bb, bb, bb, bb, bb};
  for (int k = 0; k < HDIM; ++k) {
    float w = W[(size_t)k * DDIM + d];
#pragma unroll
    for (int q = 0; q < 8; ++q) acc[q] = fmaf(rows[q][k], w, acc[q]);
  }
#pragma unroll
  for (int q = 0; q < 8; ++q) {
    int g = g0 + q;
    if (g < G) out[(size_t)g * DDIM + d] = acc[q];
  }
}

// ---------- launch ----------

extern "C" void kernel_launch(void* const* d_in, const int* in_sizes, int n_in,
                              void* d_out, int out_size, void* d_ws, size_t ws_size,
                              hipStream_t stream) {
  const int N = in_sizes[0];
  const int E = in_sizes[1] / 2;
  const int G = out_size / DDIM;

  const int* node_ids = (const int*)d_in[0];
  const int* src = (const int*)d_in[1];
  const int* dst = src + E;
  const int* batch = (const int*)d_in[2];
  const float* emb = (const float*)d_in[3];
  const float* Ws = (const float*)d_in[4];
  const float* bs = (const float*)d_in[5];
  const float* gam = (const float*)d_in[6];
  const float* bet = (const float*)d_in[7];
  const float* mu = (const float*)d_in[8];
  const float* va = (const float*)d_in[9];
  const float* pW = (const float*)d_in[10];
  const float* pb = (const float*)d_in[11];
  float* out = (float*)d_out;

  size_t o = 0;
  auto alloc = [&](size_t bytes) -> void* {
    size_t start = (o + 255) & ~(size_t)255;
    o = start + bytes;
    return (void*)((char*)d_ws + start);
  };
  // zbuf (cnt|cur|total) and pooled are contiguous -> single memset zeroes both
  int* zbuf = (int*)alloc((size_t)(2 * N + 1) * 4);
  int* cnt = zbuf;
  int* cur = zbuf + N;
  int* total = zbuf + 2 * N;
  float* pooled = (float*)alloc((size_t)G * HDIM * 4);
  size_t zbytes = (size_t)((char*)pooled - (char*)zbuf) + (size_t)G * HDIM * 4;
  float* dinv = (float*)alloc((size_t)N * 4);
  int* off = (int*)alloc((size_t)N * 4);
  int2* ninfo = (int2*)alloc((size_t)N * 8);
  int2* edata = (int2*)alloc((size_t)E * 8);
  float* embW = (float*)alloc((size_t)VSZ * HDIM * 4);
  float* Ac = (float*)alloc((size_t)3 * HDIM * 4);
  float* Bc = (float*)alloc((size_t)3 * HDIM * 4);
  int* goff = (int*)alloc((size_t)(G + 1) * 4);
  unsigned short* Wtb = (unsigned short*)alloc((size_t)2 * HDIM * HDIM * 2);
  unsigned short* bufX = (unsigned short*)alloc((size_t)N * HDIM * 2);
  unsigned short* bufY = (unsigned short*)alloc((size_t)N * HDIM * 2);

  int gE = (E + 255) / 256;
  int NB = (N + 255) / 256;
  int NGB = (G + 1 + 255) / 256;

  // CSR build
  hipMemsetAsync(zbuf, 0, zbytes, stream);
  k_count<<<gE, 256, 0, stream>>>(dst, cnt, E);
  k_alloc<<<NB, 256, 0, stream>>>(cnt, off, dinv, ninfo, node_ids, total, N);
  k_fill<<<gE, 256, 0, stream>>>(src, dst, ninfo, off, cur, edata, E);

  // fused precomputes (wcvt x2 + embW + bnc + goff)
  k_prep<<<145 + NGB, 256, 0, stream>>>(emb, Ws, bs, gam, bet, mu, va, batch,
                                        embW, Ac, Bc, Wtb, goff, G, N);

  // layer 1 (fused: aggregate 14-row table + BN + ReLU) -> bf16, grid-stride
  int gs = 2048;
  k_layer1<<<gs, 256, 0, stream>>>(node_ids, embW, off, cnt, edata, dinv,
                                   Ac, Bc, bufX, N);

  // layers 2,3: aggregate (grid-stride) then MFMA GEMM + BN + ReLU
  int gm = (N + BM - 1) / BM;
  int nwg = gm * (HDIM / BN);  // 1-D swizzled grid
  k_agg<<<gs, 256, 0, stream>>>(bufX, off, cnt, edata, dinv, bufY, N);
  k_gemm_mfma<false><<<nwg, 256, 0, stream>>>(bufY, Wtb, Ac + HDIM, Bc + HDIM,
                                              bufX, pooled, batch, N);
  k_agg<<<gs, 256, 0, stream>>>(bufX, off, cnt, edata, dinv, bufY, N);
  // layer 3: pooling fused into the epilogue (no node-feature write)
  k_gemm_mfma<true><<<nwg, 256, 0, stream>>>(bufY, Wtb + HDIM * HDIM, Ac + 2 * HDIM,
                                             Bc + 2 * HDIM, bufX, pooled, batch, N);

  // projection (divides by counts)
  k_proj<<<(G + 7) / 8, 128, 0, stream>>>(pooled, goff, pW, pb, out, G);
}

// Round 17
// 285.675 us; speedup vs baseline: 1.0806x; 1.0806x over previous
//
#include <hip/hip_runtime.h>

#define HDIM 256
#define DDIM 128
#define VSZ 14

typedef __bf16 bf16x8 __attribute__((ext_vector_type(8)));
typedef float f32x4 __attribute__((ext_vector_type(4)));

static __device__ __forceinline__ unsigned short f2bf(float f) {
  unsigned u = __builtin_bit_cast(unsigned, f);
  u += 0x7FFF + ((u >> 16) & 1);  // round-to-nearest-even
  return (unsigned short)(u >> 16);
}
static __device__ __forceinline__ float bf2f(unsigned short u) {
  unsigned x = ((unsigned)u) << 16;
  return __builtin_bit_cast(float, x);
}
static __device__ __forceinline__ unsigned pack2(float a, float b) {
  return (unsigned)f2bf(a) | ((unsigned)f2bf(b) << 16);
}
// unpack 8 bf16 (as uint4) -> 8 f32
static __device__ __forceinline__ void ub8(uint4 p, float* o) {
  o[0] = __builtin_bit_cast(float, p.x << 16);
  o[1] = __builtin_bit_cast(float, p.x & 0xFFFF0000u);
  o[2] = __builtin_bit_cast(float, p.y << 16);
  o[3] = __builtin_bit_cast(float, p.y & 0xFFFF0000u);
  o[4] = __builtin_bit_cast(float, p.z << 16);
  o[5] = __builtin_bit_cast(float, p.z & 0xFFFF0000u);
  o[6] = __builtin_bit_cast(float, p.w << 16);
  o[7] = __builtin_bit_cast(float, p.w & 0xFFFF0000u);
}

// ---------- CSR construction ----------

__global__ void k_count(const int* __restrict__ dst, int* __restrict__ cnt, int E) {
  int i = blockIdx.x * 256 + threadIdx.x;
  if (i < E) atomicAdd(&cnt[dst[i]], 1);
}

// block-local scan + one atomic per block for the base; emits dinv + packed node info
__global__ void k_alloc(const int* __restrict__ cnt, int* __restrict__ off,
                        float* __restrict__ dinv, int2* __restrict__ ninfo,
                        const int* __restrict__ ids, int* __restrict__ total, int n) {
  __shared__ int s[256];
  __shared__ int base;
  int i = blockIdx.x * 256 + threadIdx.x;
  int c = (i < n) ? cnt[i] : 0;
  if (i < n) {
    float dv = rsqrtf((float)(c + 1));  // +1 self-loop
    dinv[i] = dv;
    int2 inf;
    inf.x = ids[i];
    inf.y = __builtin_bit_cast(int, dv);
    ninfo[i] = inf;
  }
  s[threadIdx.x] = c;
  __syncthreads();
  for (int d = 1; d < 256; d <<= 1) {
    int add = (threadIdx.x >= d) ? s[threadIdx.x - d] : 0;
    __syncthreads();
    s[threadIdx.x] += add;
    __syncthreads();
  }
  if (threadIdx.x == 255) base = atomicAdd(total, s[255]);
  __syncthreads();
  if (i < n) off[i] = base + s[threadIdx.x] - c;
}

// packed edge record: {src | id<<24, dinv(src) bits} (8 B)
__global__ void k_fill(const int* __restrict__ src, const int* __restrict__ dst,
                       const int2* __restrict__ ninfo, const int* __restrict__ off,
                       int* __restrict__ cur, int2* __restrict__ edata, int E) {
  int i = blockIdx.x * 256 + threadIdx.x;
  if (i >= E) return;
  int d = dst[i];
  int p = off[d] + atomicAdd(&cur[d], 1);
  int s = src[i];
  int2 inf = ninfo[s];
  int2 v;
  v.x = s | (inf.x << 24);
  v.y = inf.y;
  edata[p] = v;
}

// ---------- fused prologue precomputes ----------
// blocks [0,128): W transpose+cvt; [128,142): embW; [142,145): BN; [145,..): goff

__global__ __launch_bounds__(256) void k_prep(
    const float* __restrict__ emb, const float* __restrict__ Ws,
    const float* __restrict__ bs, const float* __restrict__ gam,
    const float* __restrict__ bet, const float* __restrict__ mu,
    const float* __restrict__ va, const int* __restrict__ batch,
    float* __restrict__ embW, float* __restrict__ Ac, float* __restrict__ Bc,
    unsigned short* __restrict__ Wtb, int* __restrict__ goff, int G, int n) {
  int b = blockIdx.x;
  if (b < 128) {
    __shared__ float tile[32][33];
    int layer = b >> 6;
    int tb = b & 63;
    int bx = (tb & 7) * 32, by = (tb >> 3) * 32;
    const float* W = Ws + (size_t)(layer + 1) * HDIM * HDIM;
    unsigned short* Wt = Wtb + (size_t)layer * HDIM * HDIM;
    int tx = threadIdx.x & 31, ty = threadIdx.x >> 5;
#pragma unroll
    for (int i = 0; i < 4; ++i)
      tile[ty + i * 8][tx] = W[(size_t)(by + ty + i * 8) * HDIM + bx + tx];
    __syncthreads();
#pragma unroll
    for (int i = 0; i < 4; ++i)
      Wt[(size_t)(bx + ty + i * 8) * HDIM + by + tx] = f2bf(tile[tx][ty + i * 8]);
  } else if (b < 142) {
    int t = b - 128, j = threadIdx.x;
    float acc = 0.f;
    for (int k = 0; k < HDIM; ++k) acc = fmaf(emb[t * HDIM + k], Ws[k * HDIM + j], acc);
    embW[t * HDIM + j] = acc;
  } else if (b < 145) {
    int i = (b - 142) * HDIM + threadIdx.x;
    float a = gam[i] * rsqrtf(va[i] + 1e-5f);
    Ac[i] = a;
    Bc[i] = (bs[i] - mu[i]) * a + bet[i];
  } else {
    int g = (b - 145) * 256 + threadIdx.x;
    if (g > G) return;
    int lo = 0, hi = n;
    while (lo < hi) {
      int mid = (lo + hi) >> 1;
      if (batch[mid] < g) lo = mid + 1;
      else hi = mid;
    }
    goff[g] = lo;
  }
}

// ---------- layer 1: aggregate bf16 14-row table (LDS) + BN + ReLU -> bf16 ----------

__global__ __launch_bounds__(256) void k_layer1(
    const int* __restrict__ ids, const float* __restrict__ embW,
    const int* __restrict__ off, const int* __restrict__ deg,
    const int2* __restrict__ edata, const float* __restrict__ dinv,
    const float* __restrict__ A, const float* __restrict__ B,
    unsigned short* __restrict__ Y, int n) {
  __shared__ unsigned short lw[VSZ * HDIM];
  for (int i = threadIdx.x; i < VSZ * HDIM; i += 256) lw[i] = f2bf(embW[i]);
  __syncthreads();
  int j = (threadIdx.x & 31) * 8;
  float4 a0 = *reinterpret_cast<const float4*>(&A[j]);
  float4 a1 = *reinterpret_cast<const float4*>(&A[j + 4]);
  float4 b0 = *reinterpret_cast<const float4*>(&B[j]);
  float4 b1 = *reinterpret_cast<const float4*>(&B[j + 4]);
  int nb = (n + 7) >> 3;
  for (int b = blockIdx.x; b < nb; b += gridDim.x) {
    int v = b * 8 + (threadIdx.x >> 5);
    if (v >= n) continue;
    float dv = dinv[v];
    float s = dv * dv;
    float acc[8], m[8];
    uint4 x = *reinterpret_cast<const uint4*>(&lw[ids[v] * HDIM + j]);
    ub8(x, acc);
#pragma unroll
    for (int i = 0; i < 8; ++i) acc[i] *= s;
    int e = off[v], e1 = e + deg[v];
    for (; e + 3 < e1; e += 4) {
      int2 d0 = edata[e], d1 = edata[e + 1], d2 = edata[e + 2], d3 = edata[e + 3];
      uint4 g0 = *reinterpret_cast<const uint4*>(&lw[((unsigned)d0.x >> 24) * HDIM + j]);
      uint4 g1 = *reinterpret_cast<const uint4*>(&lw[((unsigned)d1.x >> 24) * HDIM + j]);
      uint4 g2 = *reinterpret_cast<const uint4*>(&lw[((unsigned)d2.x >> 24) * HDIM + j]);
      uint4 g3 = *reinterpret_cast<const uint4*>(&lw[((unsigned)d3.x >> 24) * HDIM + j]);
      float w0 = dv * __builtin_bit_cast(float, d0.y);
      float w1 = dv * __builtin_bit_cast(float, d1.y);
      float w2 = dv * __builtin_bit_cast(float, d2.y);
      float w3 = dv * __builtin_bit_cast(float, d3.y);
      ub8(g0, m);
#pragma unroll
      for (int i = 0; i < 8; ++i) acc[i] = fmaf(w0, m[i], acc[i]);
      ub8(g1, m);
#pragma unroll
      for (int i = 0; i < 8; ++i) acc[i] = fmaf(w1, m[i], acc[i]);
      ub8(g2, m);
#pragma unroll
      for (int i = 0; i < 8; ++i) acc[i] = fmaf(w2, m[i], acc[i]);
      ub8(g3, m);
#pragma unroll
      for (int i = 0; i < 8; ++i) acc[i] = fmaf(w3, m[i], acc[i]);
    }
    for (; e < e1; ++e) {
      int2 d0 = edata[e];
      uint4 g0 = *reinterpret_cast<const uint4*>(&lw[((unsigned)d0.x >> 24) * HDIM + j]);
      float w0 = dv * __builtin_bit_cast(float, d0.y);
      ub8(g0, m);
#pragma unroll
      for (int i = 0; i < 8; ++i) acc[i] = fmaf(w0, m[i], acc[i]);
    }
    float o[8];
    o[0] = fmaxf(fmaf(acc[0], a0.x, b0.x), 0.f);
    o[1] = fmaxf(fmaf(acc[1], a0.y, b0.y), 0.f);
    o[2] = fmaxf(fmaf(acc[2], a0.z, b0.z), 0.f);
    o[3] = fmaxf(fmaf(acc[3], a0.w, b0.w), 0.f);
    o[4] = fmaxf(fmaf(acc[4], a1.x, b1.x), 0.f);
    o[5] = fmaxf(fmaf(acc[5], a1.y, b1.y), 0.f);
    o[6] = fmaxf(fmaf(acc[6], a1.z, b1.z), 0.f);
    o[7] = fmaxf(fmaf(acc[7], a1.w, b1.w), 0.f);
    uint4 st;
    st.x = pack2(o[0], o[1]);
    st.y = pack2(o[2], o[3]);
    st.z = pack2(o[4], o[5]);
    st.w = pack2(o[6], o[7]);
    *reinterpret_cast<uint4*>(&Y[(size_t)v * HDIM + j]) = st;
  }
}

// ---------- aggregation: bf16 gather -> bf16 out, half-wave per node, grid-stride ----------

__global__ __launch_bounds__(256) void k_agg(
    const unsigned short* __restrict__ X, const int* __restrict__ off,
    const int* __restrict__ deg, const int2* __restrict__ edata,
    const float* __restrict__ dinv, unsigned short* __restrict__ Yb, int n) {
  int j = (threadIdx.x & 31) * 8;
  int nb = (n + 7) >> 3;
  for (int b = blockIdx.x; b < nb; b += gridDim.x) {
    int v = b * 8 + (threadIdx.x >> 5);
    if (v >= n) continue;
    float dv = dinv[v];
    float s = dv * dv;
    float acc[8], m[8];
    uint4 x = *reinterpret_cast<const uint4*>(&X[(size_t)v * HDIM + j]);
    ub8(x, acc);
#pragma unroll
    for (int i = 0; i < 8; ++i) acc[i] *= s;
    int e = off[v], e1 = e + deg[v];
    for (; e + 3 < e1; e += 4) {
      int2 d0 = edata[e], d1 = edata[e + 1], d2 = edata[e + 2], d3 = edata[e + 3];
      uint4 g0 = *reinterpret_cast<const uint4*>(&X[(size_t)(d0.x & 0xFFFFFF) * HDIM + j]);
      uint4 g1 = *reinterpret_cast<const uint4*>(&X[(size_t)(d1.x & 0xFFFFFF) * HDIM + j]);
      uint4 g2 = *reinterpret_cast<const uint4*>(&X[(size_t)(d2.x & 0xFFFFFF) * HDIM + j]);
      uint4 g3 = *reinterpret_cast<const uint4*>(&X[(size_t)(d3.x & 0xFFFFFF) * HDIM + j]);
      float w0 = dv * __builtin_bit_cast(float, d0.y);
      float w1 = dv * __builtin_bit_cast(float, d1.y);
      float w2 = dv * __builtin_bit_cast(float, d2.y);
      float w3 = dv * __builtin_bit_cast(float, d3.y);
      ub8(g0, m);
#pragma unroll
      for (int i = 0; i < 8; ++i) acc[i] = fmaf(w0, m[i], acc[i]);
      ub8(g1, m);
#pragma unroll
      for (int i = 0; i < 8; ++i) acc[i] = fmaf(w1, m[i], acc[i]);
      ub8(g2, m);
#pragma unroll
      for (int i = 0; i < 8; ++i) acc[i] = fmaf(w2, m[i], acc[i]);
      ub8(g3, m);
#pragma unroll
      for (int i = 0; i < 8; ++i) acc[i] = fmaf(w3, m[i], acc[i]);
    }
    for (; e < e1; ++e) {
      int2 d0 = edata[e];
      uint4 g0 = *reinterpret_cast<const uint4*>(&X[(size_t)(d0.x & 0xFFFFFF) * HDIM + j]);
      float w0 = dv * __builtin_bit_cast(float, d0.y);
      ub8(g0, m);
#pragma unroll
      for (int i = 0; i < 8; ++i) acc[i] = fmaf(w0, m[i], acc[i]);
    }
    uint4 st;
    st.x = pack2(acc[0], acc[1]);
    st.y = pack2(acc[2], acc[3]);
    st.z = pack2(acc[4], acc[5]);
    st.w = pack2(acc[6], acc[7]);
    *reinterpret_cast<uint4*>(&Yb[(size_t)v * HDIM + j]) = st;
  }
}

// ---------- bf16 MFMA GEMM (M x 256) @ (256 x 256) + BN + ReLU ----------
// Round-15 K-loop (BK=32, LDS-staged, proven 46.7us) + XCD swizzle.
// Epilogue stages C in TWO 64-row halves (Cs[64][LDC] = 17.4 KB) so the LDS
// envelope is the 20.5 KB A/B staging, not the 34.8 KB full C-stage ->
// ~7 blocks/CU instead of 4 (round-15 counters: occupancy 22%, latency-bound).
// POOL=false: -> bf16 Y rows; POOL=true: -> segmented sums into pooled[G][256].

#define BM 128
#define BN 128
#define BK 32
#define LDK 40   // A/B staging k-stride (elements)
#define LDC 136  // C-stage row stride (elements)

template <bool POOL>
__global__ __launch_bounds__(256) void k_gemm_mfma(
    const unsigned short* __restrict__ Xb, const unsigned short* __restrict__ Wt,
    const float* __restrict__ Asc, const float* __restrict__ Bsh,
    unsigned short* __restrict__ Y, float* __restrict__ pooled,
    const int* __restrict__ batch, int M) {
  __shared__ uint4 smem4[1280];  // 20480 B: A/B staging; overlaid by Cs[64][136]
  __shared__ int gid[BM];
  unsigned short* As = reinterpret_cast<unsigned short*>(smem4);
  unsigned short* Bs = As + BM * LDK;
  unsigned short* Cs = As;
  int t = threadIdx.x;

  // bijective XCD swizzle (m204): orig -> wgid so consecutive wgid share an XCD
  int nwg = gridDim.x;
  int qq = nwg >> 3, rr = nwg & 7;
  int xcd = blockIdx.x & 7, idx = blockIdx.x >> 3;
  int wg = (xcd < rr ? xcd * (qq + 1) : rr * (qq + 1) + (xcd - rr) * qq) + idx;
  int m0 = (wg >> 1) * BM;
  int n0 = (wg & 1) * BN;

  int l = t & 63, w = t >> 6;
  int wm = w & 1, wn = w >> 1;
  int cl = l & 15, q = l >> 4;
  int r0 = t >> 2;
  int kc = (t & 3) * 8;

  if (POOL && t < BM) {
    int gr = m0 + t;
    gid[t] = (gr < M) ? batch[gr] : -1;  // covered by first K-loop barrier
  }

  f32x4 acc[4][4];
  f32x4 zf = {0.f, 0.f, 0.f, 0.f};
#pragma unroll
  for (int i = 0; i < 4; ++i)
#pragma unroll
    for (int jj = 0; jj < 4; ++jj) acc[i][jj] = zf;

  int arow0 = m0 + r0;      if (arow0 > M - 1) arow0 = M - 1;
  int arow1 = m0 + r0 + 64; if (arow1 > M - 1) arow1 = M - 1;
  int brow0 = n0 + r0, brow1 = n0 + r0 + 64;

  for (int k0 = 0; k0 < HDIM; k0 += BK) {
    uint4 a0 = *reinterpret_cast<const uint4*>(&Xb[(size_t)arow0 * HDIM + k0 + kc]);
    uint4 a1 = *reinterpret_cast<const uint4*>(&Xb[(size_t)arow1 * HDIM + k0 + kc]);
    uint4 b0 = *reinterpret_cast<const uint4*>(&Wt[(size_t)brow0 * HDIM + k0 + kc]);
    uint4 b1 = *reinterpret_cast<const uint4*>(&Wt[(size_t)brow1 * HDIM + k0 + kc]);
    __syncthreads();
    *reinterpret_cast<uint4*>(&As[r0 * LDK + kc]) = a0;
    *reinterpret_cast<uint4*>(&As[(r0 + 64) * LDK + kc]) = a1;
    *reinterpret_cast<uint4*>(&Bs[r0 * LDK + kc]) = b0;
    *reinterpret_cast<uint4*>(&Bs[(r0 + 64) * LDK + kc]) = b1;
    __syncthreads();
    bf16x8 af[4], bfr[4];
#pragma unroll
    for (int i = 0; i < 4; ++i)
      af[i] = *reinterpret_cast<const bf16x8*>(&As[(wm * 64 + i * 16 + cl) * LDK + q * 8]);
#pragma unroll
    for (int jj = 0; jj < 4; ++jj)
      bfr[jj] = *reinterpret_cast<const bf16x8*>(&Bs[(wn * 64 + jj * 16 + cl) * LDK + q * 8]);
#pragma unroll
    for (int i = 0; i < 4; ++i)
#pragma unroll
      for (int jj = 0; jj < 4; ++jj)
        acc[i][jj] = __builtin_amdgcn_mfma_f32_16x16x32_bf16(af[i], bfr[jj], acc[i][jj], 0, 0, 0);
  }

  // ---- epilogue: BN + ReLU -> LDS C-stage, TWO 64-row halves ----
#pragma unroll
  for (int h = 0; h < 2; ++h) {
    __syncthreads();  // prev half's reads (or K-loop LDS reads) complete
    if (wm == h) {
#pragma unroll
      for (int jj = 0; jj < 4; ++jj) {
        int col = wn * 64 + jj * 16 + cl;
        float as = Asc[n0 + col], bsv = Bsh[n0 + col];
#pragma unroll
        for (int i = 0; i < 4; ++i) {
          int rowb = i * 16 + q * 4;  // local row within the half
#pragma unroll
          for (int r = 0; r < 4; ++r)
            Cs[(rowb + r) * LDC + col] = f2bf(fmaxf(fmaf(acc[i][jj][r], as, bsv), 0.f));
        }
      }
    }
    __syncthreads();
    if (!POOL) {
#pragma unroll
      for (int c = 0; c < 4; ++c) {
        int idx2 = t + 256 * c;          // 0..1023 : 64 rows x 16 uint4-chunks
        int row = idx2 >> 4, cq = (idx2 & 15) * 8;
        int gr = m0 + h * 64 + row;
        if (gr < M)
          *reinterpret_cast<uint4*>(&Y[(size_t)gr * HDIM + n0 + cq]) =
              *reinterpret_cast<const uint4*>(&Cs[row * LDC + cq]);
      }
    } else {
      // segmented column-sum over this half; gid in LDS, fixed-trip loop
      int col = t & 127;
      int rbeg = (t >> 7) * 32;
      float sum = 0.f;
      int gprev = -1;
#pragma unroll 8
      for (int rr2 = 0; rr2 < 32; ++rr2) {
        int r = rbeg + rr2;
        int g = gid[h * 64 + r];
        if (g != gprev) {
          if (gprev >= 0) atomicAdd(&pooled[(size_t)gprev * HDIM + n0 + col], sum);
          sum = 0.f;
          gprev = g;
        }
        if (g >= 0) sum += bf2f(Cs[r * LDC + col]);
      }
      if (gprev >= 0) atomicAdd(&pooled[(size_t)gprev * HDIM + n0 + col], sum);
    }
  }
}

// ---------- final projection (divides pooled sums by graph size) ----------

__global__ __launch_bounds__(128) void k_proj(
    const float* __restrict__ P, const int* __restrict__ goff,
    const float* __restrict__ W, const float* __restrict__ bias,
    float* __restrict__ out, int G) {
  __shared__ float rows[8][HDIM];
  __shared__ float sinv[8];
  int g0 = blockIdx.x * 8;
  if (threadIdx.x < 8) {
    int g = g0 + threadIdx.x;
    float c = (g < G) ? (float)(goff[g + 1] - goff[g]) : 1.f;
    sinv[threadIdx.x] = 1.f / fmaxf(c, 1.f);
  }
  __syncthreads();
  for (int i = threadIdx.x; i < 8 * HDIM; i += 128) {
    int qg = i >> 8;
    int g = g0 + qg;
    rows[qg][i & 255] = (g < G) ? P[(size_t)g * HDIM + (i & 255)] * sinv[qg] : 0.f;
  }
  __syncthreads();
  int d = threadIdx.x;
  float bb = bias[d];
  float acc[8] = {bb, bb, bb, bb, bb, bb, bb, bb};
  for (int k = 0; k < HDIM; ++k) {
    float w = W[(size_t)k * DDIM + d];
#pragma unroll
    for (int q = 0; q < 8; ++q) acc[q] = fmaf(rows[q][k], w, acc[q]);
  }
#pragma unroll
  for (int q = 0; q < 8; ++q) {
    int g = g0 + q;
    if (g < G) out[(size_t)g * DDIM + d] = acc[q];
  }
}

// ---------- launch ----------

extern "C" void kernel_launch(void* const* d_in, const int* in_sizes, int n_in,
                              void* d_out, int out_size, void* d_ws, size_t ws_size,
                              hipStream_t stream) {
  const int N = in_sizes[0];
  const int E = in_sizes[1] / 2;
  const int G = out_size / DDIM;

  const int* node_ids = (const int*)d_in[0];
  const int* src = (const int*)d_in[1];
  const int* dst = src + E;
  const int* batch = (const int*)d_in[2];
  const float* emb = (const float*)d_in[3];
  const float* Ws = (const float*)d_in[4];
  const float* bs = (const float*)d_in[5];
  const float* gam = (const float*)d_in[6];
  const float* bet = (const float*)d_in[7];
  const float* mu = (const float*)d_in[8];
  const float* va = (const float*)d_in[9];
  const float* pW = (const float*)d_in[10];
  const float* pb = (const float*)d_in[11];
  float* out = (float*)d_out;

  size_t o = 0;
  auto alloc = [&](size_t bytes) -> void* {
    size_t start = (o + 255) & ~(size_t)255;
    o = start + bytes;
    return (void*)((char*)d_ws + start);
  };
  // zbuf (cnt|cur|total) and pooled are contiguous -> single memset zeroes both
  int* zbuf = (int*)alloc((size_t)(2 * N + 1) * 4);
  int* cnt = zbuf;
  int* cur = zbuf + N;
  int* total = zbuf + 2 * N;
  float* pooled = (float*)alloc((size_t)G * HDIM * 4);
  size_t zbytes = (size_t)((char*)pooled - (char*)zbuf) + (size_t)G * HDIM * 4;
  float* dinv = (float*)alloc((size_t)N * 4);
  int* off = (int*)alloc((size_t)N * 4);
  int2* ninfo = (int2*)alloc((size_t)N * 8);
  int2* edata = (int2*)alloc((size_t)E * 8);
  float* embW = (float*)alloc((size_t)VSZ * HDIM * 4);
  float* Ac = (float*)alloc((size_t)3 * HDIM * 4);
  float* Bc = (float*)alloc((size_t)3 * HDIM * 4);
  int* goff = (int*)alloc((size_t)(G + 1) * 4);
  unsigned short* Wtb = (unsigned short*)alloc((size_t)2 * HDIM * HDIM * 2);
  unsigned short* bufX = (unsigned short*)alloc((size_t)N * HDIM * 2);
  unsigned short* bufY = (unsigned short*)alloc((size_t)N * HDIM * 2);

  int gE = (E + 255) / 256;
  int NB = (N + 255) / 256;
  int NGB = (G + 1 + 255) / 256;

  // CSR build
  hipMemsetAsync(zbuf, 0, zbytes, stream);
  k_count<<<gE, 256, 0, stream>>>(dst, cnt, E);
  k_alloc<<<NB, 256, 0, stream>>>(cnt, off, dinv, ninfo, node_ids, total, N);
  k_fill<<<gE, 256, 0, stream>>>(src, dst, ninfo, off, cur, edata, E);

  // fused precomputes (wcvt x2 + embW + bnc + goff)
  k_prep<<<145 + NGB, 256, 0, stream>>>(emb, Ws, bs, gam, bet, mu, va, batch,
                                        embW, Ac, Bc, Wtb, goff, G, N);

  // layer 1 (fused: aggregate 14-row table + BN + ReLU) -> bf16, grid-stride
  int gs = 2048;
  k_layer1<<<gs, 256, 0, stream>>>(node_ids, embW, off, cnt, edata, dinv,
                                   Ac, Bc, bufX, N);

  // layers 2,3: aggregate (grid-stride) then MFMA GEMM + BN + ReLU
  int gm = (N + BM - 1) / BM;
  int nwg = gm * (HDIM / BN);  // 1-D swizzled grid
  k_agg<<<gs, 256, 0, stream>>>(bufX, off, cnt, edata, dinv, bufY, N);
  k_gemm_mfma<false><<<nwg, 256, 0, stream>>>(bufY, Wtb, Ac + HDIM, Bc + HDIM,
                                              bufX, pooled, batch, N);
  k_agg<<<gs, 256, 0, stream>>>(bufX, off, cnt, edata, dinv, bufY, N);
  // layer 3: pooling fused into the epilogue (no node-feature write)
  k_gemm_mfma<true><<<nwg, 256, 0, stream>>>(bufY, Wtb + HDIM * HDIM, Ac + 2 * HDIM,
                                             Bc + 2 * HDIM, bufX, pooled, batch, N);

  // projection (divides by counts)
  k_proj<<<(G + 7) / 8, 128, 0, stream>>>(pooled, goff, pW, pb, out, G);
}

// Round 19
// 257.607 us; speedup vs baseline: 1.1983x; 1.1090x over previous
//
#include <hip/hip_runtime.h>

#define HDIM 256
#define DDIM 128
#define VSZ 14

typedef __bf16 bf16x8 __attribute__((ext_vector_type(8)));
typedef float f32x4 __attribute__((ext_vector_type(4)));

static __device__ __forceinline__ unsigned short f2bf(float f) {
  unsigned u = __builtin_bit_cast(unsigned, f);
  u += 0x7FFF + ((u >> 16) & 1);  // round-to-nearest-even
  return (unsigned short)(u >> 16);
}
static __device__ __forceinline__ float bf2f(unsigned short u) {
  unsigned x = ((unsigned)u) << 16;
  return __builtin_bit_cast(float, x);
}
static __device__ __forceinline__ unsigned pack2(float a, float b) {
  return (unsigned)f2bf(a) | ((unsigned)f2bf(b) << 16);
}
// unpack 8 bf16 (as uint4) -> 8 f32
static __device__ __forceinline__ void ub8(uint4 p, float* o) {
  o[0] = __builtin_bit_cast(float, p.x << 16);
  o[1] = __builtin_bit_cast(float, p.x & 0xFFFF0000u);
  o[2] = __builtin_bit_cast(float, p.y << 16);
  o[3] = __builtin_bit_cast(float, p.y & 0xFFFF0000u);
  o[4] = __builtin_bit_cast(float, p.z << 16);
  o[5] = __builtin_bit_cast(float, p.z & 0xFFFF0000u);
  o[6] = __builtin_bit_cast(float, p.w << 16);
  o[7] = __builtin_bit_cast(float, p.w & 0xFFFF0000u);
}

// ---------- CSR construction ----------

__global__ void k_count(const int* __restrict__ dst, int* __restrict__ cnt, int E) {
  int i = blockIdx.x * 256 + threadIdx.x;
  if (i < E) atomicAdd(&cnt[dst[i]], 1);
}

// block-local scan + one atomic per block for the base; emits dinv + packed node info
__global__ void k_alloc(const int* __restrict__ cnt, int* __restrict__ off,
                        float* __restrict__ dinv, int2* __restrict__ ninfo,
                        const int* __restrict__ ids, int* __restrict__ total, int n) {
  __shared__ int s[256];
  __shared__ int base;
  int i = blockIdx.x * 256 + threadIdx.x;
  int c = (i < n) ? cnt[i] : 0;
  if (i < n) {
    float dv = rsqrtf((float)(c + 1));  // +1 self-loop
    dinv[i] = dv;
    int2 inf;
    inf.x = ids[i];
    inf.y = __builtin_bit_cast(int, dv);
    ninfo[i] = inf;
  }
  s[threadIdx.x] = c;
  __syncthreads();
  for (int d = 1; d < 256; d <<= 1) {
    int add = (threadIdx.x >= d) ? s[threadIdx.x - d] : 0;
    __syncthreads();
    s[threadIdx.x] += add;
    __syncthreads();
  }
  if (threadIdx.x == 255) base = atomicAdd(total, s[255]);
  __syncthreads();
  if (i < n) off[i] = base + s[threadIdx.x] - c;
}

// packed edge record: {src | id<<24, dinv(src) bits} (8 B)
__global__ void k_fill(const int* __restrict__ src, const int* __restrict__ dst,
                       const int2* __restrict__ ninfo, const int* __restrict__ off,
                       int* __restrict__ cur, int2* __restrict__ edata, int E) {
  int i = blockIdx.x * 256 + threadIdx.x;
  if (i >= E) return;
  int d = dst[i];
  int p = off[d] + atomicAdd(&cur[d], 1);
  int s = src[i];
  int2 inf = ninfo[s];
  int2 v;
  v.x = s | (inf.x << 24);
  v.y = inf.y;
  edata[p] = v;
}

// ---------- fused prologue precomputes ----------
// blocks [0,128): W transpose+cvt; [128,142): embW; [142,145): BN; [145,..): goff

__global__ __launch_bounds__(256) void k_prep(
    const float* __restrict__ emb, const float* __restrict__ Ws,
    const float* __restrict__ bs, const float* __restrict__ gam,
    const float* __restrict__ bet, const float* __restrict__ mu,
    const float* __restrict__ va, const int* __restrict__ batch,
    float* __restrict__ embW, float* __restrict__ Ac, float* __restrict__ Bc,
    unsigned short* __restrict__ Wtb, int* __restrict__ goff, int G, int n) {
  int b = blockIdx.x;
  if (b < 128) {
    __shared__ float tile[32][33];
    int layer = b >> 6;
    int tb = b & 63;
    int bx = (tb & 7) * 32, by = (tb >> 3) * 32;
    const float* W = Ws + (size_t)(layer + 1) * HDIM * HDIM;
    unsigned short* Wt = Wtb + (size_t)layer * HDIM * HDIM;
    int tx = threadIdx.x & 31, ty = threadIdx.x >> 5;
#pragma unroll
    for (int i = 0; i < 4; ++i)
      tile[ty + i * 8][tx] = W[(size_t)(by + ty + i * 8) * HDIM + bx + tx];
    __syncthreads();
#pragma unroll
    for (int i = 0; i < 4; ++i)
      Wt[(size_t)(bx + ty + i * 8) * HDIM + by + tx] = f2bf(tile[tx][ty + i * 8]);
  } else if (b < 142) {
    int t = b - 128, j = threadIdx.x;
    float acc = 0.f;
    for (int k = 0; k < HDIM; ++k) acc = fmaf(emb[t * HDIM + k], Ws[k * HDIM + j], acc);
    embW[t * HDIM + j] = acc;
  } else if (b < 145) {
    int i = (b - 142) * HDIM + threadIdx.x;
    float a = gam[i] * rsqrtf(va[i] + 1e-5f);
    Ac[i] = a;
    Bc[i] = (bs[i] - mu[i]) * a + bet[i];
  } else {
    int g = (b - 145) * 256 + threadIdx.x;
    if (g > G) return;
    int lo = 0, hi = n;
    while (lo < hi) {
      int mid = (lo + hi) >> 1;
      if (batch[mid] < g) lo = mid + 1;
      else hi = mid;
    }
    goff[g] = lo;
  }
}

// ---------- layer 1: aggregate bf16 14-row table (LDS) + BN + ReLU -> bf16 ----------

__global__ __launch_bounds__(256) void k_layer1(
    const int* __restrict__ ids, const float* __restrict__ embW,
    const int* __restrict__ off, const int* __restrict__ deg,
    const int2* __restrict__ edata, const float* __restrict__ dinv,
    const float* __restrict__ A, const float* __restrict__ B,
    unsigned short* __restrict__ Y, int n) {
  __shared__ unsigned short lw[VSZ * HDIM];
  for (int i = threadIdx.x; i < VSZ * HDIM; i += 256) lw[i] = f2bf(embW[i]);
  __syncthreads();
  int j = (threadIdx.x & 31) * 8;
  float4 a0 = *reinterpret_cast<const float4*>(&A[j]);
  float4 a1 = *reinterpret_cast<const float4*>(&A[j + 4]);
  float4 b0 = *reinterpret_cast<const float4*>(&B[j]);
  float4 b1 = *reinterpret_cast<const float4*>(&B[j + 4]);
  int nb = (n + 7) >> 3;
  for (int b = blockIdx.x; b < nb; b += gridDim.x) {
    int v = b * 8 + (threadIdx.x >> 5);
    if (v >= n) continue;
    float dv = dinv[v];
    float s = dv * dv;
    float acc[8], m[8];
    uint4 x = *reinterpret_cast<const uint4*>(&lw[ids[v] * HDIM + j]);
    ub8(x, acc);
#pragma unroll
    for (int i = 0; i < 8; ++i) acc[i] *= s;
    int e = off[v], e1 = e + deg[v];
    for (; e + 3 < e1; e += 4) {
      int2 d0 = edata[e], d1 = edata[e + 1], d2 = edata[e + 2], d3 = edata[e + 3];
      uint4 g0 = *reinterpret_cast<const uint4*>(&lw[((unsigned)d0.x >> 24) * HDIM + j]);
      uint4 g1 = *reinterpret_cast<const uint4*>(&lw[((unsigned)d1.x >> 24) * HDIM + j]);
      uint4 g2 = *reinterpret_cast<const uint4*>(&lw[((unsigned)d2.x >> 24) * HDIM + j]);
      uint4 g3 = *reinterpret_cast<const uint4*>(&lw[((unsigned)d3.x >> 24) * HDIM + j]);
      float w0 = dv * __builtin_bit_cast(float, d0.y);
      float w1 = dv * __builtin_bit_cast(float, d1.y);
      float w2 = dv * __builtin_bit_cast(float, d2.y);
      float w3 = dv * __builtin_bit_cast(float, d3.y);
      ub8(g0, m);
#pragma unroll
      for (int i = 0; i < 8; ++i) acc[i] = fmaf(w0, m[i], acc[i]);
      ub8(g1, m);
#pragma unroll
      for (int i = 0; i < 8; ++i) acc[i] = fmaf(w1, m[i], acc[i]);
      ub8(g2, m);
#pragma unroll
      for (int i = 0; i < 8; ++i) acc[i] = fmaf(w2, m[i], acc[i]);
      ub8(g3, m);
#pragma unroll
      for (int i = 0; i < 8; ++i) acc[i] = fmaf(w3, m[i], acc[i]);
    }
    for (; e < e1; ++e) {
      int2 d0 = edata[e];
      uint4 g0 = *reinterpret_cast<const uint4*>(&lw[((unsigned)d0.x >> 24) * HDIM + j]);
      float w0 = dv * __builtin_bit_cast(float, d0.y);
      ub8(g0, m);
#pragma unroll
      for (int i = 0; i < 8; ++i) acc[i] = fmaf(w0, m[i], acc[i]);
    }
    float o[8];
    o[0] = fmaxf(fmaf(acc[0], a0.x, b0.x), 0.f);
    o[1] = fmaxf(fmaf(acc[1], a0.y, b0.y), 0.f);
    o[2] = fmaxf(fmaf(acc[2], a0.z, b0.z), 0.f);
    o[3] = fmaxf(fmaf(acc[3], a0.w, b0.w), 0.f);
    o[4] = fmaxf(fmaf(acc[4], a1.x, b1.x), 0.f);
    o[5] = fmaxf(fmaf(acc[5], a1.y, b1.y), 0.f);
    o[6] = fmaxf(fmaf(acc[6], a1.z, b1.z), 0.f);
    o[7] = fmaxf(fmaf(acc[7], a1.w, b1.w), 0.f);
    uint4 st;
    st.x = pack2(o[0], o[1]);
    st.y = pack2(o[2], o[3]);
    st.z = pack2(o[4], o[5]);
    st.w = pack2(o[6], o[7]);
    *reinterpret_cast<uint4*>(&Y[(size_t)v * HDIM + j]) = st;
  }
}

// ---------- aggregation: bf16 gather -> bf16 out, half-wave per node, grid-stride ----------

__global__ __launch_bounds__(256) void k_agg(
    const unsigned short* __restrict__ X, const int* __restrict__ off,
    const int* __restrict__ deg, const int2* __restrict__ edata,
    const float* __restrict__ dinv, unsigned short* __restrict__ Yb, int n) {
  int j = (threadIdx.x & 31) * 8;
  int nb = (n + 7) >> 3;
  for (int b = blockIdx.x; b < nb; b += gridDim.x) {
    int v = b * 8 + (threadIdx.x >> 5);
    if (v >= n) continue;
    float dv = dinv[v];
    float s = dv * dv;
    float acc[8], m[8];
    uint4 x = *reinterpret_cast<const uint4*>(&X[(size_t)v * HDIM + j]);
    ub8(x, acc);
#pragma unroll
    for (int i = 0; i < 8; ++i) acc[i] *= s;
    int e = off[v], e1 = e + deg[v];
    for (; e + 3 < e1; e += 4) {
      int2 d0 = edata[e], d1 = edata[e + 1], d2 = edata[e + 2], d3 = edata[e + 3];
      uint4 g0 = *reinterpret_cast<const uint4*>(&X[(size_t)(d0.x & 0xFFFFFF) * HDIM + j]);
      uint4 g1 = *reinterpret_cast<const uint4*>(&X[(size_t)(d1.x & 0xFFFFFF) * HDIM + j]);
      uint4 g2 = *reinterpret_cast<const uint4*>(&X[(size_t)(d2.x & 0xFFFFFF) * HDIM + j]);
      uint4 g3 = *reinterpret_cast<const uint4*>(&X[(size_t)(d3.x & 0xFFFFFF) * HDIM + j]);
      float w0 = dv * __builtin_bit_cast(float, d0.y);
      float w1 = dv * __builtin_bit_cast(float, d1.y);
      float w2 = dv * __builtin_bit_cast(float, d2.y);
      float w3 = dv * __builtin_bit_cast(float, d3.y);
      ub8(g0, m);
#pragma unroll
      for (int i = 0; i < 8; ++i) acc[i] = fmaf(w0, m[i], acc[i]);
      ub8(g1, m);
#pragma unroll
      for (int i = 0; i < 8; ++i) acc[i] = fmaf(w1, m[i], acc[i]);
      ub8(g2, m);
#pragma unroll
      for (int i = 0; i < 8; ++i) acc[i] = fmaf(w2, m[i], acc[i]);
      ub8(g3, m);
#pragma unroll
      for (int i = 0; i < 8; ++i) acc[i] = fmaf(w3, m[i], acc[i]);
    }
    for (; e < e1; ++e) {
      int2 d0 = edata[e];
      uint4 g0 = *reinterpret_cast<const uint4*>(&X[(size_t)(d0.x & 0xFFFFFF) * HDIM + j]);
      float w0 = dv * __builtin_bit_cast(float, d0.y);
      ub8(g0, m);
#pragma unroll
      for (int i = 0; i < 8; ++i) acc[i] = fmaf(w0, m[i], acc[i]);
    }
    uint4 st;
    st.x = pack2(acc[0], acc[1]);
    st.y = pack2(acc[2], acc[3]);
    st.z = pack2(acc[4], acc[5]);
    st.w = pack2(acc[6], acc[7]);
    *reinterpret_cast<uint4*>(&Yb[(size_t)v * HDIM + j]) = st;
  }
}

// ---------- bf16 MFMA GEMM (M x 256) @ (256 x 256) + BN + ReLU ----------
// Round-15 barrier/staging structure, tile BM=64 x BN=128. LDS: staging
// A(64x40)+B(128x40) = 15360 B; C-stage Cs[64][LDC=136] = 17408 B (the
// envelope; round-18 crash was LDC=120 < BN columns -> OOB LDS writes).
// ~9 blocks/CU vs round-15's 4; acc halves to 8 f32x4.
// Tile pair {2m,2m+1} shares A rows; bijective XCD swizzle keeps the pair
// on one XCD. POOL=false -> bf16 Y rows; POOL=true -> pooled[G][256].

#define BM 64
#define BN 128
#define BK 32
#define LDK 40   // A/B staging k-stride (elements)
#define LDC 136  // C-stage row stride (elements), >= BN

template <bool POOL>
__global__ __launch_bounds__(256) void k_gemm_mfma(
    const unsigned short* __restrict__ Xb, const unsigned short* __restrict__ Wt,
    const float* __restrict__ Asc, const float* __restrict__ Bsh,
    unsigned short* __restrict__ Y, float* __restrict__ pooled,
    const int* __restrict__ batch, int M) {
  __shared__ uint4 smem4[1088];  // 17408 B: C-stage envelope; staging uses 15360 B
  __shared__ int gid[BM];
  unsigned short* As = reinterpret_cast<unsigned short*>(smem4);
  unsigned short* Bs = As + BM * LDK;
  unsigned short* Cs = As;
  int t = threadIdx.x;

  // bijective XCD swizzle (m204): orig -> wgid so consecutive wgid share an XCD
  int nwg = gridDim.x;
  int qq = nwg >> 3, rr = nwg & 7;
  int xcd = blockIdx.x & 7, idx = blockIdx.x >> 3;
  int wg = (xcd < rr ? xcd * (qq + 1) : rr * (qq + 1) + (xcd - rr) * qq) + idx;
  int m0 = (wg >> 1) * BM;
  int n0 = (wg & 1) * BN;

  int l = t & 63, w = t >> 6;
  int wm = w & 1, wn = w >> 1;   // wave: 32 m-rows (wm half) x 64 n-cols (wn half)
  int cl = l & 15, q = l >> 4;
  int r0 = t >> 2;               // 0..63 staging row
  int kc = (t & 3) * 8;          // staging k-offset

  if (POOL && t < BM) {
    int gr = m0 + t;
    gid[t] = (gr < M) ? batch[gr] : -1;  // covered by first K-loop barrier
  }

  f32x4 acc[2][4];
  f32x4 zf = {0.f, 0.f, 0.f, 0.f};
#pragma unroll
  for (int i = 0; i < 2; ++i)
#pragma unroll
    for (int jj = 0; jj < 4; ++jj) acc[i][jj] = zf;

  int arow = m0 + r0; if (arow > M - 1) arow = M - 1;
  int brow0 = n0 + r0, brow1 = n0 + r0 + 64;

  for (int k0 = 0; k0 < HDIM; k0 += BK) {
    uint4 a0 = *reinterpret_cast<const uint4*>(&Xb[(size_t)arow * HDIM + k0 + kc]);
    uint4 b0 = *reinterpret_cast<const uint4*>(&Wt[(size_t)brow0 * HDIM + k0 + kc]);
    uint4 b1 = *reinterpret_cast<const uint4*>(&Wt[(size_t)brow1 * HDIM + k0 + kc]);
    __syncthreads();
    *reinterpret_cast<uint4*>(&As[r0 * LDK + kc]) = a0;
    *reinterpret_cast<uint4*>(&Bs[r0 * LDK + kc]) = b0;
    *reinterpret_cast<uint4*>(&Bs[(r0 + 64) * LDK + kc]) = b1;
    __syncthreads();
    bf16x8 af[2], bfr[4];
#pragma unroll
    for (int i = 0; i < 2; ++i)
      af[i] = *reinterpret_cast<const bf16x8*>(&As[(wm * 32 + i * 16 + cl) * LDK + q * 8]);
#pragma unroll
    for (int jj = 0; jj < 4; ++jj)
      bfr[jj] = *reinterpret_cast<const bf16x8*>(&Bs[(wn * 64 + jj * 16 + cl) * LDK + q * 8]);
#pragma unroll
    for (int i = 0; i < 2; ++i)
#pragma unroll
      for (int jj = 0; jj < 4; ++jj)
        acc[i][jj] = __builtin_amdgcn_mfma_f32_16x16x32_bf16(af[i], bfr[jj], acc[i][jj], 0, 0, 0);
  }

  // ---- epilogue: BN + ReLU -> LDS C-stage (overlays staging) ----
  __syncthreads();  // K-loop LDS reads complete before overwrite
#pragma unroll
  for (int jj = 0; jj < 4; ++jj) {
    int col = wn * 64 + jj * 16 + cl;
    float as = Asc[n0 + col], bsv = Bsh[n0 + col];
#pragma unroll
    for (int i = 0; i < 2; ++i) {
      int rowb = wm * 32 + i * 16 + q * 4;
#pragma unroll
      for (int r = 0; r < 4; ++r)
        Cs[(rowb + r) * LDC + col] = f2bf(fmaxf(fmaf(acc[i][jj][r], as, bsv), 0.f));
    }
  }
  __syncthreads();
  if (!POOL) {
#pragma unroll
    for (int c = 0; c < 4; ++c) {
      int idx2 = t + 256 * c;            // 0..1023 : 64 rows x 16 uint4-chunks
      int row = idx2 >> 4, cq = (idx2 & 15) * 8;
      int gr = m0 + row;
      if (gr < M)
        *reinterpret_cast<uint4*>(&Y[(size_t)gr * HDIM + n0 + cq]) =
            *reinterpret_cast<const uint4*>(&Cs[row * LDC + cq]);
    }
  } else {
    // segmented column-sum; gid in LDS, fixed-trip loop (wave-uniform branches)
    int col = t & 127;
    int rbeg = (t >> 7) * 32;
    float sum = 0.f;
    int gprev = -1;
#pragma unroll 8
    for (int rr2 = 0; rr2 < 32; ++rr2) {
      int r = rbeg + rr2;
      int g = gid[r];
      if (g != gprev) {
        if (gprev >= 0) atomicAdd(&pooled[(size_t)gprev * HDIM + n0 + col], sum);
        sum = 0.f;
        gprev = g;
      }
      if (g >= 0) sum += bf2f(Cs[r * LDC + col]);
    }
    if (gprev >= 0) atomicAdd(&pooled[(size_t)gprev * HDIM + n0 + col], sum);
  }
}

// ---------- final projection (divides pooled sums by graph size) ----------

__global__ __launch_bounds__(128) void k_proj(
    const float* __restrict__ P, const int* __restrict__ goff,
    const float* __restrict__ W, const float* __restrict__ bias,
    float* __restrict__ out, int G) {
  __shared__ float rows[8][HDIM];
  __shared__ float sinv[8];
  int g0 = blockIdx.x * 8;
  if (threadIdx.x < 8) {
    int g = g0 + threadIdx.x;
    float c = (g < G) ? (float)(goff[g + 1] - goff[g]) : 1.f;
    sinv[threadIdx.x] = 1.f / fmaxf(c, 1.f);
  }
  __syncthreads();
  for (int i = threadIdx.x; i < 8 * HDIM; i += 128) {
    int qg = i >> 8;
    int g = g0 + qg;
    rows[qg][i & 255] = (g < G) ? P[(size_t)g * HDIM + (i & 255)] * sinv[qg] : 0.f;
  }
  __syncthreads();
  int d = threadIdx.x;
  float bb = bias[d];
  float acc[8] = {bb, bb, bb, bb, bb, bb, bb, bb};
  for (int k = 0; k < HDIM; ++k) {
    float w = W[(size_t)k * DDIM + d];
#pragma unroll
    for (int q = 0; q < 8; ++q) acc[q] = fmaf(rows[q][k], w, acc[q]);
  }
#pragma unroll
  for (int q = 0; q < 8; ++q) {
    int g = g0 + q;
    if (g < G) out[(size_t)g * DDIM + d] = acc[q];
  }
}

// ---------- launch ----------

extern "C" void kernel_launch(void* const* d_in, const int* in_sizes, int n_in,
                              void* d_out, int out_size, void* d_ws, size_t ws_size,
                              hipStream_t stream) {
  const int N = in_sizes[0];
  const int E = in_sizes[1] / 2;
  const int G = out_size / DDIM;

  const int* node_ids = (const int*)d_in[0];
  const int* src = (const int*)d_in[1];
  const int* dst = src + E;
  const int* batch = (const int*)d_in[2];
  const float* emb = (const float*)d_in[3];
  const float* Ws = (const float*)d_in[4];
  const float* bs = (const float*)d_in[5];
  const float* gam = (const float*)d_in[6];
  const float* bet = (const float*)d_in[7];
  const float* mu = (const float*)d_in[8];
  const float* va = (const float*)d_in[9];
  const float* pW = (const float*)d_in[10];
  const float* pb = (const float*)d_in[11];
  float* out = (float*)d_out;

  size_t o = 0;
  auto alloc = [&](size_t bytes) -> void* {
    size_t start = (o + 255) & ~(size_t)255;
    o = start + bytes;
    return (void*)((char*)d_ws + start);
  };
  // zbuf (cnt|cur|total) and pooled are contiguous -> single memset zeroes both
  int* zbuf = (int*)alloc((size_t)(2 * N + 1) * 4);
  int* cnt = zbuf;
  int* cur = zbuf + N;
  int* total = zbuf + 2 * N;
  float* pooled = (float*)alloc((size_t)G * HDIM * 4);
  size_t zbytes = (size_t)((char*)pooled - (char*)zbuf) + (size_t)G * HDIM * 4;
  float* dinv = (float*)alloc((size_t)N * 4);
  int* off = (int*)alloc((size_t)N * 4);
  int2* ninfo = (int2*)alloc((size_t)N * 8);
  int2* edata = (int2*)alloc((size_t)E * 8);
  float* embW = (float*)alloc((size_t)VSZ * HDIM * 4);
  float* Ac = (float*)alloc((size_t)3 * HDIM * 4);
  float* Bc = (float*)alloc((size_t)3 * HDIM * 4);
  int* goff = (int*)alloc((size_t)(G + 1) * 4);
  unsigned short* Wtb = (unsigned short*)alloc((size_t)2 * HDIM * HDIM * 2);
  unsigned short* bufX = (unsigned short*)alloc((size_t)N * HDIM * 2);
  unsigned short* bufY = (unsigned short*)alloc((size_t)N * HDIM * 2);

  int gE = (E + 255) / 256;
  int NB = (N + 255) / 256;
  int NGB = (G + 1 + 255) / 256;

  // CSR build
  hipMemsetAsync(zbuf, 0, zbytes, stream);
  k_count<<<gE, 256, 0, stream>>>(dst, cnt, E);
  k_alloc<<<NB, 256, 0, stream>>>(cnt, off, dinv, ninfo, node_ids, total, N);
  k_fill<<<gE, 256, 0, stream>>>(src, dst, ninfo, off, cur, edata, E);

  // fused precomputes (wcvt x2 + embW + bnc + goff)
  k_prep<<<145 + NGB, 256, 0, stream>>>(emb, Ws, bs, gam, bet, mu, va, batch,
                                        embW, Ac, Bc, Wtb, goff, G, N);

  // layer 1 (fused: aggregate 14-row table + BN + ReLU) -> bf16, grid-stride
  int gs = 2048;
  k_layer1<<<gs, 256, 0, stream>>>(node_ids, embW, off, cnt, edata, dinv,
                                   Ac, Bc, bufX, N);

  // layers 2,3: aggregate (grid-stride) then MFMA GEMM + BN + ReLU
  int gm = (N + BM - 1) / BM;
  int nwg = gm * (HDIM / BN);  // 1-D swizzled grid
  k_agg<<<gs, 256, 0, stream>>>(bufX, off, cnt, edata, dinv, bufY, N);
  k_gemm_mfma<false><<<nwg, 256, 0, stream>>>(bufY, Wtb, Ac + HDIM, Bc + HDIM,
                                              bufX, pooled, batch, N);
  k_agg<<<gs, 256, 0, stream>>>(bufX, off, cnt, edata, dinv, bufY, N);
  // layer 3: pooling fused into the epilogue (no node-feature write)
  k_gemm_mfma<true><<<nwg, 256, 0, stream>>>(bufY, Wtb + HDIM * HDIM, Ac + 2 * HDIM,
                                             Bc + 2 * HDIM, bufX, pooled, batch, N);

  // projection (divides by counts)
  k_proj<<<(G + 7) / 8, 128, 0, stream>>>(pooled, goff, pW, pb, out, G);
}